// Round 1
// baseline (441.633 us; speedup 1.0000x reference)
//
#include <hip/hip_runtime.h>

namespace {

constexpr int DIN  = 768;
constexpr int HID  = 64;
constexpr int NEXP = 6;
constexpr int BATCH = 64;
constexpr int CDIM  = 320;
constexpr int NZ    = 64;
constexpr int NTOK  = BATCH * CDIM;   // 20480

// d_out layout: x_prompted, z_prompted, loss, logits (flat, in return order)
constexpr long long XP_OFF   = 0;
constexpr long long ZP_OFF   = (long long)BATCH * (CDIM - NZ) * DIN;  // 12582912
constexpr long long LOSS_OFF = ZP_OFF + (long long)BATCH * NZ * DIN;  // 15728640
constexpr long long LG_OFF   = LOSS_OFF + 1;

// ---------------- Kernel A: gating (one wave per token) ----------------
__global__ __launch_bounds__(256) void gate_kernel(
    const float* __restrict__ x, const float* __restrict__ xi,
    const float* __restrict__ wg, float* __restrict__ out,
    float4* __restrict__ rec)
{
  int wid  = threadIdx.x >> 6;
  int lane = threadIdx.x & 63;
  int n = blockIdx.x * 4 + wid;

  float lg[NEXP];
  #pragma unroll
  for (int e = 0; e < NEXP; ++e) lg[e] = 0.f;

  const float4* xv  = reinterpret_cast<const float4*>(x  + (size_t)n * DIN);
  const float4* xiv = reinterpret_cast<const float4*>(xi + (size_t)n * DIN);
  #pragma unroll
  for (int j = 0; j < 3; ++j) {
    int f = lane + 64 * j;
    float4 a = xv[f], b = xiv[f];
    float t0 = a.x + b.x, t1 = a.y + b.y, t2 = a.z + b.z, t3 = a.w + b.w;
    int d = f * 4;
    #pragma unroll
    for (int e = 0; e < NEXP; ++e) {
      lg[e] += t0 * wg[(d + 0) * NEXP + e] + t1 * wg[(d + 1) * NEXP + e]
             + t2 * wg[(d + 2) * NEXP + e] + t3 * wg[(d + 3) * NEXP + e];
    }
  }
  // wave-wide butterfly sum (64 lanes)
  #pragma unroll
  for (int e = 0; e < NEXP; ++e) {
    float v = lg[e];
    #pragma unroll
    for (int off = 32; off >= 1; off >>= 1) v += __shfl_xor(v, off, 64);
    lg[e] = v;
  }
  // top-2 (first-occurrence ties, matching lax.top_k)
  int e0 = 0; float v0 = lg[0];
  #pragma unroll
  for (int j = 1; j < NEXP; ++j) if (lg[j] > v0) { v0 = lg[j]; e0 = j; }
  int e1 = 0; float v1 = -3.4e38f;
  #pragma unroll
  for (int j = 0; j < NEXP; ++j) if (j != e0 && lg[j] > v1) { v1 = lg[j]; e1 = j; }
  float g0 = 1.f / (1.f + expf(v1 - v0));   // softmax over [v0, v1]

  // write logits (avoid runtime-indexed register array -> cndmask select chain)
  if (lane < NEXP) {
    float myv = lg[0];
    #pragma unroll
    for (int e = 1; e < NEXP; ++e) if (lane == e) myv = lg[e];
    out[LG_OFF + (size_t)n * NEXP + lane] = myv;
  }
  if (lane == 0) rec[n] = make_float4((float)e0, (float)e1, g0, 1.f - g0);
}

// ---------------- Kernel B: selective expert matmul ----------------
constexpr int TB = 32;    // tokens per block
constexpr int CH = 128;   // d-chunk

__global__ __launch_bounds__(256) void expert_kernel(
    const float* __restrict__ x, const float* __restrict__ xi,
    const float* __restrict__ ew, const float* __restrict__ eb,
    const float4* __restrict__ rec, float* __restrict__ y)
{
  __shared__ float tok_lds[TB][CH];       // 16 KB
  __shared__ float W_lds[CH][HID];        // 32 KB
  __shared__ float y_acc[TB][HID];        // 8 KB
  __shared__ int   cnt[NEXP];
  __shared__ int   list_tok[NEXP][TB];
  __shared__ float list_gate[NEXP][TB];

  int tid = threadIdx.x;
  int t0  = blockIdx.x * TB;

  if (tid < NEXP) cnt[tid] = 0;
  __syncthreads();
  if (tid < TB) {
    float4 r = rec[t0 + tid];
    int e0 = (int)r.x, e1 = (int)r.y;
    int p0 = atomicAdd(&cnt[e0], 1);
    list_tok[e0][p0] = tid; list_gate[e0][p0] = r.z;
    int p1 = atomicAdd(&cnt[e1], 1);
    list_tok[e1][p1] = tid; list_gate[e1][p1] = r.w;
  }
  // init y with gated expert bias
  for (int idx = tid; idx < TB * HID; idx += 256) {
    int t = idx >> 6, h = idx & 63;
    float4 r = rec[t0 + t];
    y_acc[t][h] = r.z * eb[(int)r.x * HID + h] + r.w * eb[(int)r.y * HID + h];
  }

  int wid = tid >> 6, lane = tid & 63;
  for (int dc = 0; dc < DIN; dc += CH) {
    __syncthreads();  // previous chunk's compute done before tok overwrite
    for (int f = tid; f < TB * CH / 4; f += 256) {
      int t = f >> 5; int dd = (f & 31) << 2;
      float4 a = *reinterpret_cast<const float4*>(x  + (size_t)(t0 + t) * DIN + dc + dd);
      float4 b = *reinterpret_cast<const float4*>(xi + (size_t)(t0 + t) * DIN + dc + dd);
      *reinterpret_cast<float4*>(&tok_lds[t][dd]) =
          make_float4(a.x + b.x, a.y + b.y, a.z + b.z, a.w + b.w);
    }
    for (int e = 0; e < NEXP; ++e) {
      __syncthreads();  // tok staged / previous expert's compute done
      const float4* wsrc =
          reinterpret_cast<const float4*>(ew + (size_t)e * DIN * HID + (size_t)dc * HID);
      float4* wdst = reinterpret_cast<float4*>(&W_lds[0][0]);
      for (int f = tid; f < CH * HID / 4; f += 256) wdst[f] = wsrc[f];
      __syncthreads();
      int m = cnt[e];
      for (int i = wid * 2; i < m; i += 8) {
        int   ta = list_tok[e][i];
        float ga = list_gate[e][i];
        bool  two = (i + 1 < m);
        int   tb2 = two ? list_tok[e][i + 1] : ta;
        float gb  = two ? list_gate[e][i + 1] : 0.f;
        float p0 = 0.f, p1 = 0.f;
        #pragma unroll 8
        for (int d4 = 0; d4 < CH; d4 += 4) {
          float4 a = *reinterpret_cast<const float4*>(&tok_lds[ta][d4]);
          float4 b = *reinterpret_cast<const float4*>(&tok_lds[tb2][d4]);
          float w0 = W_lds[d4 + 0][lane], w1 = W_lds[d4 + 1][lane];
          float w2 = W_lds[d4 + 2][lane], w3 = W_lds[d4 + 3][lane];
          p0 += a.x * w0 + a.y * w1 + a.z * w2 + a.w * w3;
          p1 += b.x * w0 + b.y * w1 + b.z * w2 + b.w * w3;
        }
        y_acc[ta][lane] += ga * p0;
        if (two) y_acc[tb2][lane] += gb * p1;
      }
    }
  }
  __syncthreads();
  for (int idx = tid; idx < TB * HID; idx += 256) {
    int t = idx >> 6, h = idx & 63;
    y[(size_t)(t0 + t) * HID + h] = y_acc[t][h];
  }
}

// ---------------- Kernel C: FFN (y @ ffn1_w^T + b) ----------------
constexpr int TC   = 64;    // tokens per block
constexpr int DCH  = 128;   // output-d chunk
constexpr int WPAD = 133;   // 133 coprime-ish stride -> conflict-free staging & reads

__device__ inline size_t out_index(int n, int d) {
  int b = n / CDIM;
  int c = n - b * CDIM;
  if (c < NZ) return (size_t)ZP_OFF + ((size_t)(b * NZ + c)) * DIN + d;
  return (size_t)XP_OFF + ((size_t)(b * (CDIM - NZ) + (c - NZ))) * DIN + d;
}

__global__ __launch_bounds__(256) void ffn_kernel(
    const float* __restrict__ y, const float* __restrict__ fw,
    const float* __restrict__ fb, float* __restrict__ out)
{
  __shared__ float y_lds[TC][HID];      // 16 KB
  __shared__ float w_lds[HID][WPAD];    // ~34 KB

  int tid = threadIdx.x;
  int t0 = blockIdx.x * TC;
  int d0 = blockIdx.y * DCH;

  {
    const float4* src = reinterpret_cast<const float4*>(y + (size_t)t0 * HID);
    float4* dst = reinterpret_cast<float4*>(&y_lds[0][0]);
    for (int f = tid; f < TC * HID / 4; f += 256) dst[f] = src[f];
  }
  for (int f = tid; f < DCH * HID; f += 256) {
    int d = f >> 6, h = f & 63;                    // consecutive tid -> consecutive h
    w_lds[h][d] = fw[(size_t)(d0 + d) * HID + h];  // coalesced read, conflict-free write
  }
  __syncthreads();

  int dd = tid & 127;
  int tg = tid >> 7;
  int d  = d0 + dd;
  float bias = fb[d];
  for (int t = tg * 32; t < tg * 32 + 32; t += 2) {
    float acc0 = bias, acc1 = bias;
    #pragma unroll 8
    for (int h = 0; h < HID; h += 4) {
      float4 ya = *reinterpret_cast<const float4*>(&y_lds[t][h]);
      float4 yb = *reinterpret_cast<const float4*>(&y_lds[t + 1][h]);
      float w0 = w_lds[h + 0][dd], w1 = w_lds[h + 1][dd];
      float w2 = w_lds[h + 2][dd], w3 = w_lds[h + 3][dd];
      acc0 += ya.x * w0 + ya.y * w1 + ya.z * w2 + ya.w * w3;
      acc1 += yb.x * w0 + yb.y * w1 + yb.z * w2 + yb.w * w3;
    }
    out[out_index(t0 + t, d)]     = acc0;
    out[out_index(t0 + t + 1, d)] = acc1;
  }
}

// ---------------- Kernel D: load-balance loss ----------------
__global__ __launch_bounds__(256) void loss_kernel(
    const float4* __restrict__ rec, float* __restrict__ out)
{
  float imp[NEXP], ld[NEXP];
  #pragma unroll
  for (int e = 0; e < NEXP; ++e) { imp[e] = 0.f; ld[e] = 0.f; }
  for (int n = threadIdx.x; n < NTOK; n += 256) {
    float4 r = rec[n];
    int e0 = (int)r.x, e1 = (int)r.y;
    #pragma unroll
    for (int e = 0; e < NEXP; ++e) {   // branchless: keep compile-time indices
      imp[e] += (e == e0 ? r.z : 0.f) + (e == e1 ? r.w : 0.f);
      ld[e]  += (e == e0 ? 1.f : 0.f) + (e == e1 ? 1.f : 0.f);
    }
  }
  #pragma unroll
  for (int e = 0; e < NEXP; ++e) {
    float a = imp[e], b = ld[e];
    #pragma unroll
    for (int off = 32; off >= 1; off >>= 1) {
      a += __shfl_xor(a, off, 64);
      b += __shfl_xor(b, off, 64);
    }
    imp[e] = a; ld[e] = b;
  }
  __shared__ float simp[4][NEXP], sld[4][NEXP];
  int wid = threadIdx.x >> 6, lane = threadIdx.x & 63;
  if (lane == 0) {
    #pragma unroll
    for (int e = 0; e < NEXP; ++e) { simp[wid][e] = imp[e]; sld[wid][e] = ld[e]; }
  }
  __syncthreads();
  if (threadIdx.x == 0) {
    float It[NEXP], Lt[NEXP];
    float mi = 0.f, ml = 0.f;
    #pragma unroll
    for (int e = 0; e < NEXP; ++e) {
      It[e] = simp[0][e] + simp[1][e] + simp[2][e] + simp[3][e];
      Lt[e] = sld[0][e] + sld[1][e] + sld[2][e] + sld[3][e];
      mi += It[e]; ml += Lt[e];
    }
    mi /= NEXP; ml /= NEXP;
    float vi = 0.f, vl = 0.f;
    #pragma unroll
    for (int e = 0; e < NEXP; ++e) {
      vi += (It[e] - mi) * (It[e] - mi);
      vl += (Lt[e] - ml) * (Lt[e] - ml);
    }
    vi /= NEXP; vl /= NEXP;
    out[LOSS_OFF] = vi / (mi * mi + 1e-10f) + vl / (ml * ml + 1e-10f);
  }
}

}  // namespace

extern "C" void kernel_launch(void* const* d_in, const int* in_sizes, int n_in,
                              void* d_out, int out_size, void* d_ws, size_t ws_size,
                              hipStream_t stream)
{
  const float* x  = (const float*)d_in[0];
  const float* xi = (const float*)d_in[1];
  const float* wg = (const float*)d_in[2];
  const float* ew = (const float*)d_in[3];
  const float* eb = (const float*)d_in[4];
  const float* fw = (const float*)d_in[5];
  const float* fb = (const float*)d_in[6];
  float* out = (float*)d_out;

  float4* rec = (float4*)d_ws;                       // 20480 * 16 B
  float*  yb  = (float*)d_ws + (size_t)NTOK * 4;     // 20480 * 64 f32

  gate_kernel<<<NTOK / 4, 256, 0, stream>>>(x, xi, wg, out, rec);
  expert_kernel<<<NTOK / TB, 256, 0, stream>>>(x, xi, ew, eb, rec, yb);
  ffn_kernel<<<dim3(NTOK / TC, DIN / DCH), 256, 0, stream>>>(yb, fw, fb, out);
  loss_kernel<<<1, 256, 0, stream>>>(rec, out);
}

// Round 2
// 126.394 us; speedup vs baseline: 3.4941x; 3.4941x over previous
//
#include <hip/hip_runtime.h>

typedef __attribute__((ext_vector_type(8))) short short8;
typedef __attribute__((ext_vector_type(4))) float f32x4;

namespace {

constexpr int DIN  = 768;
constexpr int HID  = 64;
constexpr int NEXP = 6;
constexpr int BATCH = 64;
constexpr int CDIM  = 320;
constexpr int NZ    = 64;
constexpr int NTOK  = BATCH * CDIM;   // 20480

// d_out layout: x_prompted, z_prompted, loss, logits
constexpr long long XP_OFF   = 0;
constexpr long long ZP_OFF   = (long long)BATCH * (CDIM - NZ) * DIN;  // 12582912
constexpr long long LOSS_OFF = ZP_OFF + (long long)BATCH * NZ * DIN;  // 15728640
constexpr long long LG_OFF   = LOSS_OFF + 1;

__device__ inline unsigned short f2bf(float f) {
  union { float f; unsigned u; } v{f};
  return (unsigned short)((v.u + 0x7FFFu + ((v.u >> 16) & 1u)) >> 16);  // RNE
}
__device__ inline float b2f(unsigned short s) {
  union { unsigned u; float f; } v{(unsigned)s << 16};
  return v.f;
}
__device__ inline void gload16(const void* g, void* l) {
  __builtin_amdgcn_global_load_lds(
      (const __attribute__((address_space(1))) unsigned*)g,
      (__attribute__((address_space(3))) unsigned*)l, 16, 0, 0);
}

// ---------------- K0: weight prep (expert_w -> bf16 transposed, ffn1_w -> bf16) ----
// ewb_t[e][h][k] = bf16(expert_w[e][k][h])   (so MFMA B-frag reads 8 consecutive k)
// fwb[d][h]      = bf16(ffn1_w[d][h])        (already [col][k] for the FFN GEMM)
__global__ __launch_bounds__(256) void prep_kernel(
    const float* __restrict__ ew, const float* __restrict__ fw,
    unsigned short* __restrict__ ewb_t, unsigned short* __restrict__ fwb)
{
  int b = blockIdx.x, tid = threadIdx.x;
  if (b < 72) {                       // 6 experts x 12 k-tiles of 64
    __shared__ float t_lds[64][65];
    int e = b / 12, kc = (b % 12) * 64;
    const float* src = ew + (size_t)e * DIN * HID + (size_t)kc * HID;
    #pragma unroll
    for (int it = 0; it < 16; ++it) {
      int f = it * 256 + tid; int ky = f >> 6, h = f & 63;
      t_lds[h][ky] = src[ky * 64 + h];          // coalesced read
    }
    __syncthreads();
    unsigned short* dst = ewb_t + (size_t)e * DIN * HID + kc;
    #pragma unroll
    for (int it = 0; it < 16; ++it) {
      int f = it * 256 + tid; int h = f >> 6, ky = f & 63;
      dst[(size_t)h * DIN + ky] = f2bf(t_lds[h][ky]);  // coalesced write
    }
  } else {                            // 12 blocks x 4096 elems of ffn1_w
    int base = (b - 72) * 4096;
    #pragma unroll
    for (int it = 0; it < 16; ++it) {
      int idx = base + it * 256 + tid;
      fwb[idx] = f2bf(fw[idx]);
    }
  }
}

// ---------------- K1: gating (fp32, one wave per token) — unchanged, verified ----
__global__ __launch_bounds__(256) void gate_kernel(
    const float* __restrict__ x, const float* __restrict__ xi,
    const float* __restrict__ wg, float* __restrict__ out,
    float4* __restrict__ rec)
{
  int wid  = threadIdx.x >> 6;
  int lane = threadIdx.x & 63;
  int n = blockIdx.x * 4 + wid;

  float lg[NEXP];
  #pragma unroll
  for (int e = 0; e < NEXP; ++e) lg[e] = 0.f;

  const float4* xv  = reinterpret_cast<const float4*>(x  + (size_t)n * DIN);
  const float4* xiv = reinterpret_cast<const float4*>(xi + (size_t)n * DIN);
  #pragma unroll
  for (int j = 0; j < 3; ++j) {
    int f = lane + 64 * j;
    float4 a = xv[f], b = xiv[f];
    float t0 = a.x + b.x, t1 = a.y + b.y, t2 = a.z + b.z, t3 = a.w + b.w;
    int d = f * 4;
    #pragma unroll
    for (int e = 0; e < NEXP; ++e) {
      lg[e] += t0 * wg[(d + 0) * NEXP + e] + t1 * wg[(d + 1) * NEXP + e]
             + t2 * wg[(d + 2) * NEXP + e] + t3 * wg[(d + 3) * NEXP + e];
    }
  }
  #pragma unroll
  for (int e = 0; e < NEXP; ++e) {
    float v = lg[e];
    #pragma unroll
    for (int off = 32; off >= 1; off >>= 1) v += __shfl_xor(v, off, 64);
    lg[e] = v;
  }
  int e0 = 0; float v0 = lg[0];
  #pragma unroll
  for (int j = 1; j < NEXP; ++j) if (lg[j] > v0) { v0 = lg[j]; e0 = j; }
  int e1 = 0; float v1 = -3.4e38f;
  #pragma unroll
  for (int j = 0; j < NEXP; ++j) if (j != e0 && lg[j] > v1) { v1 = lg[j]; e1 = j; }
  float g0 = 1.f / (1.f + expf(v1 - v0));

  if (lane < NEXP) {
    float myv = lg[0];
    #pragma unroll
    for (int e = 1; e < NEXP; ++e) if (lane == e) myv = lg[e];
    out[LG_OFF + (size_t)n * NEXP + lane] = myv;
  }
  if (lane == 0) rec[n] = make_float4((float)e0, (float)e1, g0, 1.f - g0);
}

// ---------------- K2: dense all-expert bf16 MFMA GEMM + gated combine ----------
// C[64 tok][384] = (x+xi)_bf16 @ W_all; epilogue: y = g0*(h[e0]+b) + g1*(h[e1]+b)
// 512 threads = 8 waves (2 wm x 4 wn); wave tile 32x96; 16x16x32 bf16 MFMA.
// LDS: A [64][64] bf16 swizzled (8 KB) + B [384][64] bf16 swizzled (48 KB).
__global__ __launch_bounds__(512) void moe_kernel(
    const float* __restrict__ x, const float* __restrict__ xi,
    const unsigned short* __restrict__ ewb_t, const float* __restrict__ eb,
    const float4* __restrict__ rec, unsigned short* __restrict__ yb)
{
  __shared__ __align__(16) char smem[57344];
  char* sA = smem;            // 8192 B
  char* sB = smem + 8192;     // 49152 B

  int tid = threadIdx.x, lane = tid & 63, wid = tid >> 6;
  int qw = lane >> 4, l15 = lane & 15;
  int wm = wid >> 2, wn = wid & 3;
  int t0 = blockIdx.x * 64;

  f32x4 acc[2][6];
  #pragma unroll
  for (int m = 0; m < 2; ++m)
    #pragma unroll
    for (int n = 0; n < 6; ++n) acc[m][n] = (f32x4){0.f, 0.f, 0.f, 0.f};

  // fragment byte offsets (thread-constant): swizzle slot ^= row&7
  int aoff[2][2], boff[6][2];
  #pragma unroll
  for (int m = 0; m < 2; ++m) {
    int row = wm * 32 + m * 16 + l15;
    #pragma unroll
    for (int kk = 0; kk < 2; ++kk)
      aoff[m][kk] = row * 128 + (((kk * 4 + qw) ^ (row & 7)) << 4);
  }
  #pragma unroll
  for (int n = 0; n < 6; ++n) {
    int row = wn * 96 + n * 16 + l15;
    #pragma unroll
    for (int kk = 0; kk < 2; ++kk)
      boff[n][kk] = row * 128 + (((kk * 4 + qw) ^ (row & 7)) << 4);
  }

  // A staging addresses (thread-constant)
  int ra = tid >> 3, sa = tid & 7;
  const float* xrow  = x  + (size_t)(t0 + ra) * DIN + sa * 8;
  const float* xirow = xi + (size_t)(t0 + ra) * DIN + sa * 8;
  char* adst = sA + ra * 128 + ((sa ^ (ra & 7)) << 4);

  // preload chunk 0 (T14: issue-early)
  float4 pa0 = *(const float4*)(xrow);
  float4 pa1 = *(const float4*)(xrow + 4);
  float4 pb0 = *(const float4*)(xirow);
  float4 pb1 = *(const float4*)(xirow + 4);

  for (int kc = 0; kc < 12; ++kc) {
    __syncthreads();   // previous chunk's MFMA reads done
    // B stage: global_load_lds with pre-swizzled source (linear LDS dest)
    #pragma unroll
    for (int it = 0; it < 6; ++it) {
      int F = it * 512 + tid;
      int r = F >> 3, s = F & 7;
      gload16(ewb_t + (size_t)r * DIN + kc * 64 + ((s ^ (r & 7)) * 8),
              sB + (it * 512 + wid * 64) * 16);
    }
    // A: write preloaded regs (fp32 add -> bf16) to swizzled LDS
    short8 av;
    av[0] = (short)f2bf(pa0.x + pb0.x); av[1] = (short)f2bf(pa0.y + pb0.y);
    av[2] = (short)f2bf(pa0.z + pb0.z); av[3] = (short)f2bf(pa0.w + pb0.w);
    av[4] = (short)f2bf(pa1.x + pb1.x); av[5] = (short)f2bf(pa1.y + pb1.y);
    av[6] = (short)f2bf(pa1.z + pb1.z); av[7] = (short)f2bf(pa1.w + pb1.w);
    *(short8*)adst = av;
    // preload next chunk (in flight across the barrier + MFMA phase)
    if (kc < 11) {
      pa0 = *(const float4*)(xrow + (kc + 1) * 64);
      pa1 = *(const float4*)(xrow + (kc + 1) * 64 + 4);
      pb0 = *(const float4*)(xirow + (kc + 1) * 64);
      pb1 = *(const float4*)(xirow + (kc + 1) * 64 + 4);
    }
    __syncthreads();   // staging (vmcnt+lgkm drained by barrier)
    #pragma unroll
    for (int kk = 0; kk < 2; ++kk) {
      short8 af[2], bf[6];
      #pragma unroll
      for (int m = 0; m < 2; ++m) af[m] = *(const short8*)(sA + aoff[m][kk]);
      #pragma unroll
      for (int n = 0; n < 6; ++n) bf[n] = *(const short8*)(sB + boff[n][kk]);
      #pragma unroll
      for (int m = 0; m < 2; ++m)
        #pragma unroll
        for (int n = 0; n < 6; ++n)
          acc[m][n] = __builtin_amdgcn_mfma_f32_16x16x32_bf16(af[m], bf[n], acc[m][n], 0, 0, 0);
    }
  }

  __syncthreads();
  // epilogue: all-expert h -> LDS bf16 [64][392] (padded rows: conflict-light)
  unsigned short* hl = (unsigned short*)smem;
  #pragma unroll
  for (int m = 0; m < 2; ++m)
    #pragma unroll
    for (int n = 0; n < 6; ++n)
      #pragma unroll
      for (int i = 0; i < 4; ++i) {
        int row = wm * 32 + m * 16 + qw * 4 + i;
        int col = wn * 96 + n * 16 + l15;
        hl[row * 392 + col] = f2bf(acc[m][n][i]);
      }
  __syncthreads();
  // gated combine -> y bf16
  int t = tid >> 3, j0 = (tid & 7) * 8;
  float4 rr = rec[t0 + t];
  int e0 = (int)rr.x, e1 = (int)rr.y;
  float g0 = rr.z, g1 = rr.w;
  short8 h0 = *(const short8*)(hl + t * 392 + e0 * 64 + j0);
  short8 h1 = *(const short8*)(hl + t * 392 + e1 * 64 + j0);
  const float4* ep0 = (const float4*)(eb + e0 * 64 + j0);
  const float4* ep1 = (const float4*)(eb + e1 * 64 + j0);
  float4 b0a = ep0[0], b0b = ep0[1], b1a = ep1[0], b1b = ep1[1];
  float be0[8] = {b0a.x, b0a.y, b0a.z, b0a.w, b0b.x, b0b.y, b0b.z, b0b.w};
  float be1[8] = {b1a.x, b1a.y, b1a.z, b1a.w, b1b.x, b1b.y, b1b.z, b1b.w};
  short8 ov;
  #pragma unroll
  for (int j = 0; j < 8; ++j) {
    float v = g0 * (b2f((unsigned short)h0[j]) + be0[j])
            + g1 * (b2f((unsigned short)h1[j]) + be1[j]);
    ov[j] = (short)f2bf(v);
  }
  *(short8*)(yb + (size_t)(t0 + t) * 64 + j0) = ov;
}

// ---------------- K3: FFN bf16 MFMA: out[n][d] = y[n] @ fwb[d] + fb[d] ----------
// 256 threads = 4 waves (2x2); tile 128 tok x 128 d; K=64 (single chunk).
__global__ __launch_bounds__(256) void ffn_kernel(
    const unsigned short* __restrict__ yb, const unsigned short* __restrict__ fwb,
    const float* __restrict__ fb, float* __restrict__ out)
{
  __shared__ __align__(16) char smem[32768];
  __shared__ int rb[128];
  char* sA = smem;            // y    [128][64] bf16 swizzled
  char* sB = smem + 16384;    // fwb  [128][64] bf16 swizzled

  int tid = threadIdx.x, lane = tid & 63, wid = tid >> 6;
  int qw = lane >> 4, l15 = lane & 15;
  int wm = wid >> 1, wn = wid & 1;
  int t0 = blockIdx.x * 128, d0 = blockIdx.y * 128;

  if (tid < 128) {   // out row base (z/x split)
    int n = t0 + tid; int bb = n / CDIM; int c = n - bb * CDIM;
    rb[tid] = (c < NZ) ? (int)(ZP_OFF + (size_t)(bb * NZ + c) * DIN)
                       : (int)(XP_OFF + (size_t)(bb * (CDIM - NZ) + (c - NZ)) * DIN);
  }
  #pragma unroll
  for (int it = 0; it < 4; ++it) {
    int F = it * 256 + tid;
    int r = F >> 3, s = F & 7;
    gload16(yb  + (size_t)(t0 + r) * 64 + ((s ^ (r & 7)) * 8),
            sA + (it * 256 + wid * 64) * 16);
    gload16(fwb + (size_t)(d0 + r) * 64 + ((s ^ (r & 7)) * 8),
            sB + (it * 256 + wid * 64) * 16);
  }
  __syncthreads();

  f32x4 acc[4][4];
  #pragma unroll
  for (int m = 0; m < 4; ++m)
    #pragma unroll
    for (int n = 0; n < 4; ++n) acc[m][n] = (f32x4){0.f, 0.f, 0.f, 0.f};

  #pragma unroll
  for (int kk = 0; kk < 2; ++kk) {
    short8 af[4], bw[4];
    #pragma unroll
    for (int m = 0; m < 4; ++m) {
      int row = wm * 64 + m * 16 + l15;
      af[m] = *(const short8*)(sA + row * 128 + (((kk * 4 + qw) ^ (row & 7)) << 4));
    }
    #pragma unroll
    for (int n = 0; n < 4; ++n) {
      int row = wn * 64 + n * 16 + l15;
      bw[n] = *(const short8*)(sB + row * 128 + (((kk * 4 + qw) ^ (row & 7)) << 4));
    }
    #pragma unroll
    for (int m = 0; m < 4; ++m)
      #pragma unroll
      for (int n = 0; n < 4; ++n)
        acc[m][n] = __builtin_amdgcn_mfma_f32_16x16x32_bf16(af[m], bw[n], acc[m][n], 0, 0, 0);
  }

  #pragma unroll
  for (int n = 0; n < 4; ++n) {
    int col = d0 + wn * 64 + n * 16 + l15;
    float bias = fb[col];
    #pragma unroll
    for (int m = 0; m < 4; ++m)
      #pragma unroll
      for (int i = 0; i < 4; ++i) {
        int rl = wm * 64 + m * 16 + qw * 4 + i;
        out[(size_t)rb[rl] + col] = acc[m][n][i] + bias;
      }
  }
}

// ---------------- K4: load-balance loss — unchanged, verified ----------
__global__ __launch_bounds__(256) void loss_kernel(
    const float4* __restrict__ rec, float* __restrict__ out)
{
  float imp[NEXP], ld[NEXP];
  #pragma unroll
  for (int e = 0; e < NEXP; ++e) { imp[e] = 0.f; ld[e] = 0.f; }
  for (int n = threadIdx.x; n < NTOK; n += 256) {
    float4 r = rec[n];
    int e0 = (int)r.x, e1 = (int)r.y;
    #pragma unroll
    for (int e = 0; e < NEXP; ++e) {
      imp[e] += (e == e0 ? r.z : 0.f) + (e == e1 ? r.w : 0.f);
      ld[e]  += (e == e0 ? 1.f : 0.f) + (e == e1 ? 1.f : 0.f);
    }
  }
  #pragma unroll
  for (int e = 0; e < NEXP; ++e) {
    float a = imp[e], b = ld[e];
    #pragma unroll
    for (int off = 32; off >= 1; off >>= 1) {
      a += __shfl_xor(a, off, 64);
      b += __shfl_xor(b, off, 64);
    }
    imp[e] = a; ld[e] = b;
  }
  __shared__ float simp[4][NEXP], sld[4][NEXP];
  int wid = threadIdx.x >> 6, lane = threadIdx.x & 63;
  if (lane == 0) {
    #pragma unroll
    for (int e = 0; e < NEXP; ++e) { simp[wid][e] = imp[e]; sld[wid][e] = ld[e]; }
  }
  __syncthreads();
  if (threadIdx.x == 0) {
    float It[NEXP], Lt[NEXP];
    float mi = 0.f, ml = 0.f;
    #pragma unroll
    for (int e = 0; e < NEXP; ++e) {
      It[e] = simp[0][e] + simp[1][e] + simp[2][e] + simp[3][e];
      Lt[e] = sld[0][e] + sld[1][e] + sld[2][e] + sld[3][e];
      mi += It[e]; ml += Lt[e];
    }
    mi /= NEXP; ml /= NEXP;
    float vi = 0.f, vl = 0.f;
    #pragma unroll
    for (int e = 0; e < NEXP; ++e) {
      vi += (It[e] - mi) * (It[e] - mi);
      vl += (Lt[e] - ml) * (Lt[e] - ml);
    }
    vi /= NEXP; vl /= NEXP;
    out[LOSS_OFF] = vi / (mi * mi + 1e-10f) + vl / (ml * ml + 1e-10f);
  }
}

}  // namespace

extern "C" void kernel_launch(void* const* d_in, const int* in_sizes, int n_in,
                              void* d_out, int out_size, void* d_ws, size_t ws_size,
                              hipStream_t stream)
{
  const float* x  = (const float*)d_in[0];
  const float* xi = (const float*)d_in[1];
  const float* wg = (const float*)d_in[2];
  const float* ew = (const float*)d_in[3];
  const float* eb = (const float*)d_in[4];
  const float* fw = (const float*)d_in[5];
  const float* fb = (const float*)d_in[6];
  float* out = (float*)d_out;

  char* w = (char*)d_ws;
  float4*         rec   = (float4*)w;                               // 327,680 B
  unsigned short* yb    = (unsigned short*)(w + 327680);            // 2,621,440 B
  unsigned short* ewb_t = (unsigned short*)(w + 327680 + 2621440);  // 589,824 B
  unsigned short* fwb   = (unsigned short*)(w + 327680 + 2621440 + 589824); // 98,304 B

  prep_kernel<<<84, 256, 0, stream>>>(ew, fw, ewb_t, fwb);
  gate_kernel<<<NTOK / 4, 256, 0, stream>>>(x, xi, wg, out, rec);
  moe_kernel<<<NTOK / 64, 512, 0, stream>>>(x, xi, ewb_t, eb, rec, yb);
  ffn_kernel<<<dim3(160, 6), 256, 0, stream>>>(yb, fwb, fb, out);
  loss_kernel<<<1, 256, 0, stream>>>(rec, out);
}

// Round 3
// 99.748 us; speedup vs baseline: 4.4275x; 1.2671x over previous
//
#include <hip/hip_runtime.h>

typedef __attribute__((ext_vector_type(8))) short short8;
typedef __attribute__((ext_vector_type(4))) short short4v;
typedef __attribute__((ext_vector_type(4))) float f32x4;

namespace {

constexpr int DIN  = 768;
constexpr int HID  = 64;
constexpr int NEXP = 6;
constexpr int BATCH = 64;
constexpr int CDIM  = 320;
constexpr int NZ    = 64;
constexpr int NTOK  = BATCH * CDIM;   // 20480

// d_out layout: x_prompted, z_prompted, loss, logits
constexpr long long XP_OFF   = 0;
constexpr long long ZP_OFF   = (long long)BATCH * (CDIM - NZ) * DIN;  // 12582912
constexpr long long LOSS_OFF = ZP_OFF + (long long)BATCH * NZ * DIN;  // 15728640
constexpr long long LG_OFF   = LOSS_OFF + 1;

__device__ inline unsigned short f2bf(float f) {
  union { float f; unsigned u; } v{f};
  return (unsigned short)((v.u + 0x7FFFu + ((v.u >> 16) & 1u)) >> 16);  // RNE
}
__device__ inline float b2f(unsigned short s) {
  union { unsigned u; float f; } v{(unsigned)s << 16};
  return v.f;
}
__device__ inline void gload16(const void* g, void* l) {
  __builtin_amdgcn_global_load_lds(
      (const __attribute__((address_space(1))) unsigned*)g,
      (__attribute__((address_space(3))) unsigned*)l, 16, 0, 0);
}

// ---------------- K0: weight prep ----------------
// ewb_t[e][h][k] = bf16(expert_w[e][k][h]); fwb[d][h] = bf16(ffn1_w[d][h]);
// wgT[e][d] = fp32 w_gate[d][e]  (for fused gate accumulation)
__global__ __launch_bounds__(256) void prep_kernel(
    const float* __restrict__ ew, const float* __restrict__ fw,
    const float* __restrict__ wg,
    unsigned short* __restrict__ ewb_t, unsigned short* __restrict__ fwb,
    float* __restrict__ wgT)
{
  int b = blockIdx.x, tid = threadIdx.x;
  if (b < 72) {                       // 6 experts x 12 k-tiles of 64
    __shared__ float t_lds[64][65];
    int e = b / 12, kc = (b % 12) * 64;
    const float* src = ew + (size_t)e * DIN * HID + (size_t)kc * HID;
    #pragma unroll
    for (int it = 0; it < 16; ++it) {
      int f = it * 256 + tid; int ky = f >> 6, h = f & 63;
      t_lds[h][ky] = src[ky * 64 + h];
    }
    __syncthreads();
    unsigned short* dst = ewb_t + (size_t)e * DIN * HID + kc;
    #pragma unroll
    for (int it = 0; it < 16; ++it) {
      int f = it * 256 + tid; int h = f >> 6, ky = f & 63;
      dst[(size_t)h * DIN + ky] = f2bf(t_lds[h][ky]);
    }
  } else if (b < 84) {                // ffn1_w -> bf16
    int base = (b - 72) * 4096;
    #pragma unroll
    for (int it = 0; it < 16; ++it) {
      int idx = base + it * 256 + tid;
      fwb[idx] = f2bf(fw[idx]);
    }
  } else {                            // w_gate transpose fp32
    for (int idx = tid; idx < NEXP * DIN; idx += 256) {
      int e = idx / DIN, d = idx - e * DIN;
      wgT[e * DIN + d] = wg[d * NEXP + e];
    }
  }
}

// ---------------- K1: fused gate + dense-expert GEMM + combine + FFN ----------
// Block: 64 tokens, 512 threads (8 waves, wm(2) x wn(4)).
// Phase 1: K-loop 24 chunks of BK=32, dbuf A(4KB)+B(24KB); gate logits in fp32
//          from the A-prefetch registers.  Swizzle (64B rows): slot ^= (row>>1)&3.
// Phase 2: epilogue combine (h -> y) via LDS, then FFN 6 d-chunks of 128 with
//          dbuf fwb; 128B-row swizzle slot ^= row&7 (proven round-2).
__global__ __launch_bounds__(512) void fused_kernel(
    const float* __restrict__ x, const float* __restrict__ xi,
    const float* __restrict__ wgT,
    const unsigned short* __restrict__ ewb_t, const float* __restrict__ eb,
    const unsigned short* __restrict__ fwb, const float* __restrict__ fb,
    float* __restrict__ out, float4* __restrict__ rec_g)
{
  __shared__ __align__(16) char smem[57344];   // sA dbuf 8KB | sB dbuf 48KB ; reused later
  __shared__ float4 rec_lds[64];
  __shared__ int    rb[64];

  int tid = threadIdx.x, lane = tid & 63, wid = tid >> 6;
  int qw = lane >> 4, l15 = lane & 15;
  int wm = wid >> 2, wn = wid & 3;
  int t0 = blockIdx.x * 64;

  if (tid < 64) {
    int n = t0 + tid, bb = n / CDIM, c = n - bb * CDIM;
    rb[tid] = (c < NZ) ? (int)(ZP_OFF + (size_t)(bb * NZ + c) * DIN)
                       : (int)(XP_OFF + (size_t)(bb * (CDIM - NZ) + (c - NZ)) * DIN);
  }

  f32x4 acc[2][6];
  #pragma unroll
  for (int m = 0; m < 2; ++m)
    #pragma unroll
    for (int n = 0; n < 6; ++n) acc[m][n] = (f32x4){0.f, 0.f, 0.f, 0.f};

  // fragment byte offsets (BK=32: 64B rows, 4 slots, swizzle ^ (row>>1)&3)
  int aoff[2], boff[6];
  #pragma unroll
  for (int m = 0; m < 2; ++m) {
    int row = wm * 32 + m * 16 + l15;
    aoff[m] = row * 64 + ((qw ^ ((row >> 1) & 3)) << 4);
  }
  #pragma unroll
  for (int n = 0; n < 6; ++n) {
    int row = wn * 96 + n * 16 + l15;
    boff[n] = row * 64 + ((qw ^ ((row >> 1) & 3)) << 4);
  }

  // A staging: thread -> token row ra, 4 floats at sa*4 within each 32-chunk
  int ra = tid >> 3, sa = tid & 7;
  const float* xrow  = x  + (size_t)(t0 + ra) * DIN + sa * 4;
  const float* xirow = xi + (size_t)(t0 + ra) * DIN + sa * 4;
  int awz = ra * 64 + ((((sa >> 1) ^ ((ra >> 1) & 3))) << 4) + (sa & 1) * 8;

  float lg[NEXP];
  #pragma unroll
  for (int e = 0; e < NEXP; ++e) lg[e] = 0.f;

  // ---- prologue: chunk 0 ----
  {
    float4 ax = *(const float4*)xrow;
    float4 iv = *(const float4*)xirow;
    #pragma unroll
    for (int it = 0; it < 3; ++it) {
      int F = it * 512 + tid, r = F >> 2, s = F & 3;
      gload16(ewb_t + (size_t)r * DIN + (s ^ ((r >> 1) & 3)) * 8,
              smem + 8192 + (it * 512 + wid * 64) * 16);
    }
    float tv0 = ax.x + iv.x, tv1 = ax.y + iv.y, tv2 = ax.z + iv.z, tv3 = ax.w + iv.w;
    #pragma unroll
    for (int e = 0; e < NEXP; ++e) {
      float4 w = *(const float4*)(wgT + e * DIN + sa * 4);
      lg[e] += tv0 * w.x + tv1 * w.y + tv2 * w.z + tv3 * w.w;
    }
    short4v av;
    av[0] = (short)f2bf(tv0); av[1] = (short)f2bf(tv1);
    av[2] = (short)f2bf(tv2); av[3] = (short)f2bf(tv3);
    *(short4v*)(smem + awz) = av;
  }
  __syncthreads();

  // ---- K-loop: 24 chunks, 1 barrier each; prefetch issued before MFMA ----
  for (int k = 0; k < 24; ++k) {
    char* cA = smem + (k & 1) * 4096;
    char* cB = smem + 8192 + (k & 1) * 24576;
    char* nA = smem + ((k + 1) & 1) * 4096;
    char* nB = smem + 8192 + ((k + 1) & 1) * 24576;

    float4 ax2, ix2;
    if (k < 23) {
      ax2 = *(const float4*)(xrow  + (k + 1) * 32);
      ix2 = *(const float4*)(xirow + (k + 1) * 32);
      #pragma unroll
      for (int it = 0; it < 3; ++it) {
        int F = it * 512 + tid, r = F >> 2, s = F & 3;
        gload16(ewb_t + (size_t)r * DIN + (k + 1) * 32 + (s ^ ((r >> 1) & 3)) * 8,
                nB + (it * 512 + wid * 64) * 16);
      }
    }

    short8 af[2], bfv[6];
    #pragma unroll
    for (int m = 0; m < 2; ++m) af[m] = *(const short8*)(cA + aoff[m]);
    #pragma unroll
    for (int n = 0; n < 6; ++n) bfv[n] = *(const short8*)(cB + boff[n]);
    #pragma unroll
    for (int m = 0; m < 2; ++m)
      #pragma unroll
      for (int n = 0; n < 6; ++n)
        acc[m][n] = __builtin_amdgcn_mfma_f32_16x16x32_bf16(af[m], bfv[n], acc[m][n], 0, 0, 0);

    if (k < 23) {
      int d0 = (k + 1) * 32 + sa * 4;
      float tv0 = ax2.x + ix2.x, tv1 = ax2.y + ix2.y,
            tv2 = ax2.z + ix2.z, tv3 = ax2.w + ix2.w;
      #pragma unroll
      for (int e = 0; e < NEXP; ++e) {
        float4 w = *(const float4*)(wgT + e * DIN + d0);
        lg[e] += tv0 * w.x + tv1 * w.y + tv2 * w.z + tv3 * w.w;
      }
      short4v av;
      av[0] = (short)f2bf(tv0); av[1] = (short)f2bf(tv1);
      av[2] = (short)f2bf(tv2); av[3] = (short)f2bf(tv3);
      *(short4v*)(nA + awz) = av;
    }
    __syncthreads();
  }

  // ---- gate finalize: reduce over the 8 threads of each token row ----
  #pragma unroll
  for (int e = 0; e < NEXP; ++e) {
    float v = lg[e];
    v += __shfl_xor(v, 1, 64);
    v += __shfl_xor(v, 2, 64);
    v += __shfl_xor(v, 4, 64);
    lg[e] = v;
  }
  if (sa == 0) {
    int e0 = 0; float v0 = lg[0];
    #pragma unroll
    for (int j = 1; j < NEXP; ++j) if (lg[j] > v0) { v0 = lg[j]; e0 = j; }
    int e1 = 0; float v1 = -3.4e38f;
    #pragma unroll
    for (int j = 0; j < NEXP; ++j) if (j != e0 && lg[j] > v1) { v1 = lg[j]; e1 = j; }
    float g0 = 1.f / (1.f + expf(v1 - v0));
    #pragma unroll
    for (int e = 0; e < NEXP; ++e)
      out[LG_OFF + (size_t)(t0 + ra) * NEXP + e] = lg[e];
    float4 r4 = make_float4((float)e0, (float)e1, g0, 1.f - g0);
    rec_lds[ra] = r4;
    rec_g[t0 + ra] = r4;
  }
  __syncthreads();

  // ---- epilogue: h -> LDS bf16 [64][392] (reuse smem) ----
  unsigned short* hl = (unsigned short*)smem;
  #pragma unroll
  for (int m = 0; m < 2; ++m)
    #pragma unroll
    for (int n = 0; n < 6; ++n)
      #pragma unroll
      for (int i = 0; i < 4; ++i) {
        int row = wm * 32 + m * 16 + qw * 4 + i;
        int col = wn * 96 + n * 16 + l15;
        hl[row * 392 + col] = f2bf(acc[m][n][i]);
      }
  __syncthreads();

  // ---- gated combine -> y (registers) ----
  int t = tid >> 3, j0 = (tid & 7) * 8;
  float4 rr = rec_lds[t];
  int e0 = (int)rr.x, e1 = (int)rr.y;
  float g0 = rr.z, g1 = rr.w;
  short8 h0 = *(const short8*)(hl + t * 392 + e0 * 64 + j0);
  short8 h1 = *(const short8*)(hl + t * 392 + e1 * 64 + j0);
  const float4* ep0 = (const float4*)(eb + e0 * 64 + j0);
  const float4* ep1 = (const float4*)(eb + e1 * 64 + j0);
  float4 b0a = ep0[0], b0b = ep0[1], b1a = ep1[0], b1b = ep1[1];
  float be0[8] = {b0a.x, b0a.y, b0a.z, b0a.w, b0b.x, b0b.y, b0b.z, b0b.w};
  float be1[8] = {b1a.x, b1a.y, b1a.z, b1a.w, b1b.x, b1b.y, b1b.z, b1b.w};
  short8 ov;
  #pragma unroll
  for (int j = 0; j < 8; ++j) {
    float v = g0 * (b2f((unsigned short)h0[j]) + be0[j])
            + g1 * (b2f((unsigned short)h1[j]) + be1[j]);
    ov[j] = (short)f2bf(v);
  }
  __syncthreads();  // h reads done; smem reusable

  // y bf16 swizzled [64][64] at smem[0..8191]; issue fwb chunk-0 staging too
  *(short8*)(smem + t * 128 + (((j0 >> 3) ^ (t & 7)) << 4)) = ov;
  #pragma unroll
  for (int it = 0; it < 2; ++it) {
    int F = it * 512 + tid, r = F >> 3, s = F & 7;
    gload16(fwb + (size_t)r * HID + (s ^ (r & 7)) * 8,
            smem + 8192 + (it * 512 + wid * 64) * 16);
  }
  __syncthreads();

  // ---- FFN: 6 d-chunks of 128, dbuf fwb ----
  for (int c = 0; c < 6; ++c) {
    char* cF = smem + 8192 + (c & 1) * 16384;
    char* nF = smem + 8192 + ((c + 1) & 1) * 16384;
    if (c < 5) {
      #pragma unroll
      for (int it = 0; it < 2; ++it) {
        int F = it * 512 + tid, r = F >> 3, s = F & 7;
        gload16(fwb + (size_t)((c + 1) * 128 + r) * HID + (s ^ (r & 7)) * 8,
                nF + (it * 512 + wid * 64) * 16);
      }
    }
    f32x4 a2[2][2];
    #pragma unroll
    for (int m = 0; m < 2; ++m)
      #pragma unroll
      for (int n = 0; n < 2; ++n) a2[m][n] = (f32x4){0.f, 0.f, 0.f, 0.f};
    #pragma unroll
    for (int kk = 0; kk < 2; ++kk) {
      short8 ay[2], bw[2];
      #pragma unroll
      for (int m = 0; m < 2; ++m) {
        int row = wm * 32 + m * 16 + l15;
        ay[m] = *(const short8*)(smem + row * 128 + (((kk * 4 + qw) ^ (row & 7)) << 4));
      }
      #pragma unroll
      for (int n = 0; n < 2; ++n) {
        int rw = wn * 32 + n * 16 + l15;
        bw[n] = *(const short8*)(cF + rw * 128 + (((kk * 4 + qw) ^ (rw & 7)) << 4));
      }
      #pragma unroll
      for (int m = 0; m < 2; ++m)
        #pragma unroll
        for (int n = 0; n < 2; ++n)
          a2[m][n] = __builtin_amdgcn_mfma_f32_16x16x32_bf16(ay[m], bw[n], a2[m][n], 0, 0, 0);
    }
    #pragma unroll
    for (int n = 0; n < 2; ++n) {
      int col = c * 128 + wn * 32 + n * 16 + l15;
      float bias = fb[col];
      #pragma unroll
      for (int m = 0; m < 2; ++m)
        #pragma unroll
        for (int i = 0; i < 4; ++i) {
          int rl = wm * 32 + m * 16 + qw * 4 + i;
          out[(size_t)rb[rl] + col] = a2[m][n][i] + bias;
        }
    }
    __syncthreads();
  }
}

// ---------------- K2: load-balance loss — unchanged, verified ----------
__global__ __launch_bounds__(256) void loss_kernel(
    const float4* __restrict__ rec, float* __restrict__ out)
{
  float imp[NEXP], ld[NEXP];
  #pragma unroll
  for (int e = 0; e < NEXP; ++e) { imp[e] = 0.f; ld[e] = 0.f; }
  for (int n = threadIdx.x; n < NTOK; n += 256) {
    float4 r = rec[n];
    int e0 = (int)r.x, e1 = (int)r.y;
    #pragma unroll
    for (int e = 0; e < NEXP; ++e) {
      imp[e] += (e == e0 ? r.z : 0.f) + (e == e1 ? r.w : 0.f);
      ld[e]  += (e == e0 ? 1.f : 0.f) + (e == e1 ? 1.f : 0.f);
    }
  }
  #pragma unroll
  for (int e = 0; e < NEXP; ++e) {
    float a = imp[e], b = ld[e];
    #pragma unroll
    for (int off = 32; off >= 1; off >>= 1) {
      a += __shfl_xor(a, off, 64);
      b += __shfl_xor(b, off, 64);
    }
    imp[e] = a; ld[e] = b;
  }
  __shared__ float simp[4][NEXP], sld[4][NEXP];
  int wid = threadIdx.x >> 6, lane = threadIdx.x & 63;
  if (lane == 0) {
    #pragma unroll
    for (int e = 0; e < NEXP; ++e) { simp[wid][e] = imp[e]; sld[wid][e] = ld[e]; }
  }
  __syncthreads();
  if (threadIdx.x == 0) {
    float It[NEXP], Lt[NEXP];
    float mi = 0.f, ml = 0.f;
    #pragma unroll
    for (int e = 0; e < NEXP; ++e) {
      It[e] = simp[0][e] + simp[1][e] + simp[2][e] + simp[3][e];
      Lt[e] = sld[0][e] + sld[1][e] + sld[2][e] + sld[3][e];
      mi += It[e]; ml += Lt[e];
    }
    mi /= NEXP; ml /= NEXP;
    float vi = 0.f, vl = 0.f;
    #pragma unroll
    for (int e = 0; e < NEXP; ++e) {
      vi += (It[e] - mi) * (It[e] - mi);
      vl += (Lt[e] - ml) * (Lt[e] - ml);
    }
    vi /= NEXP; vl /= NEXP;
    out[LOSS_OFF] = vi / (mi * mi + 1e-10f) + vl / (ml * ml + 1e-10f);
  }
}

}  // namespace

extern "C" void kernel_launch(void* const* d_in, const int* in_sizes, int n_in,
                              void* d_out, int out_size, void* d_ws, size_t ws_size,
                              hipStream_t stream)
{
  const float* x  = (const float*)d_in[0];
  const float* xi = (const float*)d_in[1];
  const float* wg = (const float*)d_in[2];
  const float* ew = (const float*)d_in[3];
  const float* eb = (const float*)d_in[4];
  const float* fw = (const float*)d_in[5];
  const float* fb = (const float*)d_in[6];
  float* out = (float*)d_out;

  char* w = (char*)d_ws;
  float4*         rec   = (float4*)w;                               // 327,680 B
  unsigned short* ewb_t = (unsigned short*)(w + 327680);            // 589,824 B
  unsigned short* fwb   = (unsigned short*)(w + 327680 + 589824);   //  98,304 B
  float*          wgT   = (float*)(w + 327680 + 589824 + 98304);    //  18,432 B

  prep_kernel<<<85, 256, 0, stream>>>(ew, fw, wg, ewb_t, fwb, wgT);
  fused_kernel<<<NTOK / 64, 512, 0, stream>>>(x, xi, wgT, ewb_t, eb, fwb, fb, out, rec);
  loss_kernel<<<1, 256, 0, stream>>>(rec, out);
}

// Round 4
// 69.826 us; speedup vs baseline: 6.3247x; 1.4285x over previous
//
#include <hip/hip_runtime.h>

typedef __attribute__((ext_vector_type(8))) short short8;
typedef __attribute__((ext_vector_type(4))) short short4v;
typedef __attribute__((ext_vector_type(4))) float f32x4;

#define VM(n) asm volatile("s_waitcnt vmcnt(" #n ")" ::: "memory")
#define LGKM0 asm volatile("s_waitcnt lgkmcnt(0)" ::: "memory")

namespace {

constexpr int DIN  = 768;
constexpr int HID  = 64;
constexpr int NEXP = 6;
constexpr int CDIM  = 320;
constexpr int NZ    = 64;
constexpr int NTOK  = 20480;

constexpr long long XP_OFF   = 0;
constexpr long long ZP_OFF   = 12582912LL;
constexpr long long LOSS_OFF = 15728640LL;
constexpr long long LG_OFF   = 15728641LL;

__device__ inline unsigned short f2bf(float f) {
  union { float f; unsigned u; } v{f};
  return (unsigned short)((v.u + 0x7FFFu + ((v.u >> 16) & 1u)) >> 16);  // RNE
}
__device__ inline float b2f(unsigned short s) {
  union { unsigned u; float f; } v{(unsigned)s << 16};
  return v.f;
}
__device__ inline void gload16(const void* g, void* l) {
  __builtin_amdgcn_global_load_lds(
      (const __attribute__((address_space(1))) unsigned*)g,
      (__attribute__((address_space(3))) unsigned*)l, 16, 0, 0);
}
// float-offset of token n's output row (also where its bf16 tok staging lives)
__device__ inline int row_base(int n) {
  int bb = n / CDIM, c = n - bb * CDIM;
  return (c < NZ) ? (int)(ZP_OFF + (long long)(bb * NZ + c) * DIN)
                  : (int)(XP_OFF + (long long)(bb * (CDIM - NZ) + (c - NZ)) * DIN);
}

// ---------------- K0: weight prep + gate + tok staging ----------------
// blocks 0-71: ewb_t[e][h][k] = bf16(expert_w[e][k][h])
// blocks 72-83: fwb = bf16(ffn1_w)
// blocks 84+ : 4 tokens each — fp32 gate logits (round-1 proven path),
//              rec, and tok=bf16(x+xi) written into d_out's own row.
__global__ __launch_bounds__(256) void pre_kernel(
    const float* __restrict__ x, const float* __restrict__ xi,
    const float* __restrict__ wg, const float* __restrict__ ew,
    const float* __restrict__ fw,
    float* __restrict__ out, float4* __restrict__ rec,
    unsigned short* __restrict__ ewb_t, unsigned short* __restrict__ fwb)
{
  int b = blockIdx.x, tid = threadIdx.x;
  __shared__ float t_lds[64][65];
  if (b < 72) {
    int e = b / 12, kc = (b % 12) * 64;
    const float* src = ew + (size_t)e * DIN * HID + (size_t)kc * HID;
    #pragma unroll
    for (int it = 0; it < 16; ++it) {
      int f = it * 256 + tid; int ky = f >> 6, h = f & 63;
      t_lds[h][ky] = src[ky * 64 + h];
    }
    __syncthreads();
    unsigned short* dst = ewb_t + (size_t)e * DIN * HID + kc;
    #pragma unroll
    for (int it = 0; it < 16; ++it) {
      int f = it * 256 + tid; int h = f >> 6, ky = f & 63;
      dst[(size_t)h * DIN + ky] = f2bf(t_lds[h][ky]);
    }
    return;
  }
  if (b < 84) {
    int base = (b - 72) * 4096;
    #pragma unroll
    for (int it = 0; it < 16; ++it) {
      int idx = base + it * 256 + tid;
      fwb[idx] = f2bf(fw[idx]);
    }
    return;
  }
  // ---- gate + tok ----
  int wid = tid >> 6, lane = tid & 63;
  int n = (b - 84) * 4 + wid;
  float lg[NEXP];
  #pragma unroll
  for (int e = 0; e < NEXP; ++e) lg[e] = 0.f;

  const float4* xv  = reinterpret_cast<const float4*>(x  + (size_t)n * DIN);
  const float4* xiv = reinterpret_cast<const float4*>(xi + (size_t)n * DIN);
  unsigned short* tk = (unsigned short*)out + (size_t)row_base(n) * 2;
  #pragma unroll
  for (int j = 0; j < 3; ++j) {
    int f = lane + 64 * j;
    float4 a = xv[f], bq = xiv[f];
    float t0 = a.x + bq.x, t1 = a.y + bq.y, t2 = a.z + bq.z, t3 = a.w + bq.w;
    short4v tv;
    tv[0] = (short)f2bf(t0); tv[1] = (short)f2bf(t1);
    tv[2] = (short)f2bf(t2); tv[3] = (short)f2bf(t3);
    *(short4v*)(tk + f * 4) = tv;
    int d = f * 4;
    #pragma unroll
    for (int e = 0; e < NEXP; ++e) {
      lg[e] += t0 * wg[(d + 0) * NEXP + e] + t1 * wg[(d + 1) * NEXP + e]
             + t2 * wg[(d + 2) * NEXP + e] + t3 * wg[(d + 3) * NEXP + e];
    }
  }
  #pragma unroll
  for (int e = 0; e < NEXP; ++e) {
    float v = lg[e];
    #pragma unroll
    for (int off = 32; off >= 1; off >>= 1) v += __shfl_xor(v, off, 64);
    lg[e] = v;
  }
  int e0 = 0; float v0 = lg[0];
  #pragma unroll
  for (int j = 1; j < NEXP; ++j) if (lg[j] > v0) { v0 = lg[j]; e0 = j; }
  int e1 = 0; float v1 = -3.4e38f;
  #pragma unroll
  for (int j = 0; j < NEXP; ++j) if (j != e0 && lg[j] > v1) { v1 = lg[j]; e1 = j; }
  float g0 = 1.f / (1.f + expf(v1 - v0));
  if (lane < NEXP) {
    float myv = lg[0];
    #pragma unroll
    for (int e = 1; e < NEXP; ++e) if (lane == e) myv = lg[e];
    out[LG_OFF + (size_t)n * NEXP + lane] = myv;
  }
  if (lane == 0) rec[n] = make_float4((float)e0, (float)e1, g0, 1.f - g0);
}

// ---------------- K1: GEMM (all experts) + combine + FFN, counted-vmcnt ----
// M=64 tok/block, N=384, BK=32, 24 phases, 512 threads (8 waves 2x4).
// LDS: A dbuf [0,8192) | B dbuf [8192,57344) | epilogue: y[0,8192),
//      h[8192,58368), fwb bufs HI=[58368,74752) LO=[8192,24576).
// Block 320 computes the load-balance loss.
__global__ __launch_bounds__(512) void moe_kernel(
    const unsigned short* __restrict__ ewb_t, const float* __restrict__ eb,
    const unsigned short* __restrict__ fwb, const float* __restrict__ fb,
    const float4* __restrict__ rec, float* __restrict__ out)
{
  __shared__ __align__(16) char smem[74752];
  __shared__ int rb[64];
  __shared__ float simp[8][NEXP], sld[8][NEXP];

  int tid = threadIdx.x, lane = tid & 63, wid = tid >> 6;
  int qw = lane >> 4, l15 = lane & 15;
  int wm = wid >> 2, wn = wid & 3;

  if (blockIdx.x == 320) {   // ---- loss ----
    float imp[NEXP], ld[NEXP];
    #pragma unroll
    for (int e = 0; e < NEXP; ++e) { imp[e] = 0.f; ld[e] = 0.f; }
    for (int n = tid; n < NTOK; n += 512) {
      float4 r = rec[n];
      int e0 = (int)r.x, e1 = (int)r.y;
      #pragma unroll
      for (int e = 0; e < NEXP; ++e) {
        imp[e] += (e == e0 ? r.z : 0.f) + (e == e1 ? r.w : 0.f);
        ld[e]  += (e == e0 ? 1.f : 0.f) + (e == e1 ? 1.f : 0.f);
      }
    }
    #pragma unroll
    for (int e = 0; e < NEXP; ++e) {
      float a = imp[e], bq = ld[e];
      #pragma unroll
      for (int off = 32; off >= 1; off >>= 1) {
        a += __shfl_xor(a, off, 64);
        bq += __shfl_xor(bq, off, 64);
      }
      imp[e] = a; ld[e] = bq;
    }
    if (lane == 0) {
      #pragma unroll
      for (int e = 0; e < NEXP; ++e) { simp[wid][e] = imp[e]; sld[wid][e] = ld[e]; }
    }
    __syncthreads();
    if (tid == 0) {
      float It[NEXP], Lt[NEXP], mi = 0.f, ml = 0.f;
      #pragma unroll
      for (int e = 0; e < NEXP; ++e) {
        It[e] = 0.f; Lt[e] = 0.f;
        #pragma unroll
        for (int w = 0; w < 8; ++w) { It[e] += simp[w][e]; Lt[e] += sld[w][e]; }
        mi += It[e]; ml += Lt[e];
      }
      mi /= NEXP; ml /= NEXP;
      float vi = 0.f, vl = 0.f;
      #pragma unroll
      for (int e = 0; e < NEXP; ++e) {
        vi += (It[e] - mi) * (It[e] - mi);
        vl += (Lt[e] - ml) * (Lt[e] - ml);
      }
      vi /= NEXP; vl /= NEXP;
      out[LOSS_OFF] = vi / (mi * mi + 1e-10f) + vl / (ml * ml + 1e-10f);
    }
    return;
  }

  int t0 = blockIdx.x * 64;
  const unsigned short* tokb = (const unsigned short*)out;

  // per-thread staging sources
  size_t b_src[3]; int b_dst[3];
  #pragma unroll
  for (int it = 0; it < 3; ++it) {
    int F = it * 512 + tid, r = F >> 2, s = F & 3;
    b_src[it] = (size_t)r * DIN + ((s ^ (r & 3) ^ ((r & 4) >> 1)) << 3);
    b_dst[it] = (it * 512 + wid * 64) * 16;
  }
  int ar = tid >> 2, as = tid & 3;
  size_t a_src = (size_t)row_base(t0 + ar) * 2 +
                 ((as ^ (ar & 3) ^ ((ar & 4) >> 1)) << 3);
  int a_dst = (wid * 64) * 16;

  if (tid < 64) rb[tid] = row_base(t0 + tid);

  // prologue: chunk 0
  #pragma unroll
  for (int it = 0; it < 3; ++it)
    gload16(ewb_t + b_src[it], smem + 8192 + b_dst[it]);
  if (tid < 256) gload16(tokb + a_src, smem + a_dst);

  f32x4 acc[2][6];
  #pragma unroll
  for (int m = 0; m < 2; ++m)
    #pragma unroll
    for (int n = 0; n < 6; ++n) acc[m][n] = (f32x4){0.f, 0.f, 0.f, 0.f};

  int aoff[2], boff[6];
  #pragma unroll
  for (int m = 0; m < 2; ++m) {
    int row = wm * 32 + m * 16 + l15;
    aoff[m] = row * 64 + ((qw ^ (row & 3) ^ ((row & 4) >> 1)) << 4);
  }
  #pragma unroll
  for (int n = 0; n < 6; ++n) {
    int row = wn * 96 + n * 16 + l15;
    boff[n] = row * 64 + ((qw ^ (row & 3) ^ ((row & 4) >> 1)) << 4);
  }

  // K-loop: 24 phases, counted vmcnt, 2 raw barriers per phase
  for (int k = 0; k < 24; ++k) {
    const char* cA = smem + (k & 1) * 4096;
    const char* cB = smem + 8192 + (k & 1) * 24576;
    char* nA = (char*)smem + ((k + 1) & 1) * 4096;
    char* nB = (char*)smem + 8192 + ((k + 1) & 1) * 24576;
    if (k < 23) {
      #pragma unroll
      for (int it = 0; it < 3; ++it)
        gload16(ewb_t + b_src[it] + (k + 1) * 32, nB + b_dst[it]);
      if (tid < 256) gload16(tokb + a_src + (k + 1) * 32, nA + a_dst);
      if (wid < 4) VM(4); else VM(3);
    } else {
      VM(0);
    }
    __builtin_amdgcn_s_barrier();
    __builtin_amdgcn_sched_barrier(0);
    short8 af[2], bfv[6];
    #pragma unroll
    for (int m = 0; m < 2; ++m) af[m] = *(const short8*)(cA + aoff[m]);
    #pragma unroll
    for (int n = 0; n < 6; ++n) bfv[n] = *(const short8*)(cB + boff[n]);
    __builtin_amdgcn_s_setprio(1);
    #pragma unroll
    for (int m = 0; m < 2; ++m)
      #pragma unroll
      for (int n = 0; n < 6; ++n)
        acc[m][n] = __builtin_amdgcn_mfma_f32_16x16x32_bf16(af[m], bfv[n], acc[m][n], 0, 0, 0);
    __builtin_amdgcn_s_setprio(0);
    __builtin_amdgcn_sched_barrier(0);
    __builtin_amdgcn_s_barrier();
  }

  // issue fwb chunk 0 into HI buffer (in flight during h/combine)
  #pragma unroll
  for (int it = 0; it < 2; ++it) {
    int F = it * 512 + tid, r = F >> 3, s = F & 7;
    gload16(fwb + (size_t)r * HID + ((s ^ (r & 7)) << 3),
            smem + 58368 + (it * 512 + wid * 64) * 16);
  }

  // h -> LDS bf16 [64][392]
  unsigned short* hl = (unsigned short*)(smem + 8192);
  #pragma unroll
  for (int m = 0; m < 2; ++m)
    #pragma unroll
    for (int n = 0; n < 6; ++n)
      #pragma unroll
      for (int i = 0; i < 4; ++i) {
        int row = wm * 32 + m * 16 + qw * 4 + i;
        int col = wn * 96 + n * 16 + l15;
        hl[row * 392 + col] = f2bf(acc[m][n][i]);
      }
  LGKM0;
  __builtin_amdgcn_s_barrier();

  // gated combine -> y bf16 (swizzled) at smem[0,8192)
  {
    int t = tid >> 3, j0 = (tid & 7) * 8;
    float4 rr = rec[t0 + t];
    int e0 = (int)rr.x, e1 = (int)rr.y;
    float g0 = rr.z, g1 = rr.w;
    short8 h0 = *(const short8*)(hl + t * 392 + e0 * 64 + j0);
    short8 h1 = *(const short8*)(hl + t * 392 + e1 * 64 + j0);
    const float4* ep0 = (const float4*)(eb + e0 * 64 + j0);
    const float4* ep1 = (const float4*)(eb + e1 * 64 + j0);
    float4 b0a = ep0[0], b0b = ep0[1], b1a = ep1[0], b1b = ep1[1];
    float be0[8] = {b0a.x, b0a.y, b0a.z, b0a.w, b0b.x, b0b.y, b0b.z, b0b.w};
    float be1[8] = {b1a.x, b1a.y, b1a.z, b1a.w, b1b.x, b1b.y, b1b.z, b1b.w};
    short8 ov;
    #pragma unroll
    for (int j = 0; j < 8; ++j) {
      float v = g0 * (b2f((unsigned short)h0[j]) + be0[j])
              + g1 * (b2f((unsigned short)h1[j]) + be1[j]);
      ov[j] = (short)f2bf(v);
    }
    *(short8*)(smem + t * 128 + ((((tid & 7)) ^ (t & 7)) << 4)) = ov;
  }
  LGKM0;
  __builtin_amdgcn_s_barrier();

  // FFN: 6 chunks of 128 cols, fwb dbuf HI/LO, counted vmcnt
  for (int c = 0; c < 6; ++c) {
    const char* cF = smem + ((c & 1) ? 8192 : 58368);
    char* nF = (char*)smem + ((c & 1) ? 58368 : 8192);
    if (c < 5) {
      #pragma unroll
      for (int it = 0; it < 2; ++it) {
        int F = it * 512 + tid, r = F >> 3, s = F & 7;
        gload16(fwb + (size_t)((c + 1) * 128 + r) * HID + ((s ^ (r & 7)) << 3),
                nF + (it * 512 + wid * 64) * 16);
      }
      VM(2);
    } else {
      VM(0);
    }
    __builtin_amdgcn_s_barrier();
    __builtin_amdgcn_sched_barrier(0);
    f32x4 a2[2][2];
    #pragma unroll
    for (int m = 0; m < 2; ++m)
      #pragma unroll
      for (int n = 0; n < 2; ++n) a2[m][n] = (f32x4){0.f, 0.f, 0.f, 0.f};
    #pragma unroll
    for (int kk = 0; kk < 2; ++kk) {
      short8 ay[2], bw[2];
      #pragma unroll
      for (int m = 0; m < 2; ++m) {
        int row = wm * 32 + m * 16 + l15;
        ay[m] = *(const short8*)(smem + row * 128 + (((kk * 4 + qw) ^ (row & 7)) << 4));
      }
      #pragma unroll
      for (int n = 0; n < 2; ++n) {
        int rw = wn * 32 + n * 16 + l15;
        bw[n] = *(const short8*)(cF + rw * 128 + (((kk * 4 + qw) ^ (rw & 7)) << 4));
      }
      __builtin_amdgcn_s_setprio(1);
      #pragma unroll
      for (int m = 0; m < 2; ++m)
        #pragma unroll
        for (int n = 0; n < 2; ++n)
          a2[m][n] = __builtin_amdgcn_mfma_f32_16x16x32_bf16(ay[m], bw[n], a2[m][n], 0, 0, 0);
      __builtin_amdgcn_s_setprio(0);
    }
    #pragma unroll
    for (int n = 0; n < 2; ++n) {
      int col = c * 128 + wn * 32 + n * 16 + l15;
      float bias = fb[col];
      #pragma unroll
      for (int m = 0; m < 2; ++m)
        #pragma unroll
        for (int i = 0; i < 4; ++i) {
          int rl = wm * 32 + m * 16 + qw * 4 + i;
          out[(size_t)rb[rl] + col] = a2[m][n][i] + bias;
        }
    }
    __builtin_amdgcn_sched_barrier(0);
    __builtin_amdgcn_s_barrier();
  }
}

}  // namespace

extern "C" void kernel_launch(void* const* d_in, const int* in_sizes, int n_in,
                              void* d_out, int out_size, void* d_ws, size_t ws_size,
                              hipStream_t stream)
{
  const float* x  = (const float*)d_in[0];
  const float* xi = (const float*)d_in[1];
  const float* wg = (const float*)d_in[2];
  const float* ew = (const float*)d_in[3];
  const float* eb = (const float*)d_in[4];
  const float* fw = (const float*)d_in[5];
  const float* fb = (const float*)d_in[6];
  float* out = (float*)d_out;

  char* w = (char*)d_ws;
  float4*         rec   = (float4*)w;                              // 327,680 B
  unsigned short* ewb_t = (unsigned short*)(w + 327680);           // 589,824 B
  unsigned short* fwb   = (unsigned short*)(w + 327680 + 589824);  //  98,304 B

  pre_kernel<<<84 + NTOK / 4, 256, 0, stream>>>(x, xi, wg, ew, fw, out, rec, ewb_t, fwb);
  moe_kernel<<<321, 512, 0, stream>>>(ewb_t, eb, fwb, fb, rec, out);
}